// Round 5
// baseline (2858.018 us; speedup 1.0000x reference)
//
#include <hip/hip_runtime.h>
#include <hip/hip_bf16.h>
#include <hip/hip_fp16.h>
#include <math.h>

#define B_DIM 8
#define C_DIM 256
#define N_DIM 2048
#define CQ 64

#define TM 64
#define TN 64
#define TK 16

typedef __attribute__((ext_vector_type(8))) short short8;   // 8 bf16 (4 VGPRs)
typedef __attribute__((ext_vector_type(4))) float floatx4;

// 3-way bf16 split: v = h + m + l + delta, |delta| <= 2^-24 |v|
__device__ inline void split_bf16x3(float v, unsigned short& h, unsigned short& m,
                                    unsigned short& l) {
  unsigned u = __float_as_uint(v);
  unsigned short hh = (unsigned short)((u + 0x7FFFu + ((u >> 16) & 1u)) >> 16);
  float fh = __uint_as_float(((unsigned)hh) << 16);
  float r1 = v - fh;  // exact
  unsigned u1 = __float_as_uint(r1);
  unsigned short mm = (unsigned short)((u1 + 0x7FFFu + ((u1 >> 16) & 1u)) >> 16);
  float fm = __uint_as_float(((unsigned)mm) << 16);
  float r2 = r1 - fm;  // exact
  unsigned u2 = __float_as_uint(r2);
  unsigned short ll = (unsigned short)((u2 + 0x7FFFu + ((u2 >> 16) & 1u)) >> 16);
  h = hh;
  m = mm;
  l = ll;
}

// pos[b,c,n] = sum_i w[c,i]*xyz[b,n,i]
__global__ void pos_kernel(const float* __restrict__ w, const float* __restrict__ xyz,
                           float* __restrict__ pos) {
  int n = blockIdx.x * blockDim.x + threadIdx.x;
  int c = blockIdx.y;
  int b = blockIdx.z;
  const float* xp = xyz + ((long long)b * N_DIM + n) * 3;
  pos[((long long)b * C_DIM + c) * N_DIM + n] =
      w[c * 3 + 0] * xp[0] + w[c * 3 + 1] * xp[1] + w[c * 3 + 2] * xp[2];
}

// Y[b,m,n] = epi( sum_k W[m,k] * (X[b,k,n] + Xadd[b,k,n]) )  -- f32, round-1 verified
__global__ void gemm_wx(const float* __restrict__ W,
                        const float* __restrict__ X, long long sxB,
                        const float* __restrict__ Xadd, long long saB,
                        const float* __restrict__ bias,
                        const float* __restrict__ bng, const float* __restrict__ bnb,
                        const float* __restrict__ bnm, const float* __restrict__ bnv,
                        const float* __restrict__ Res, long long srB,
                        float* __restrict__ Y, long long syB,
                        int M, int K) {
  const int N = N_DIM;
  int b = blockIdx.z;
  int m0 = blockIdx.y * TM;
  int n0 = blockIdx.x * TN;
  int t = threadIdx.x;
  int tx = t & 15, ty = t >> 4;
  __shared__ float As[TK][TM + 1];
  __shared__ float Bs[TK][TN];
  float acc[4][4] = {};
  const float* Xb = X + (long long)b * sxB;
  const float* Ab = Xadd ? Xadd + (long long)b * saB : nullptr;
  for (int k0 = 0; k0 < K; k0 += TK) {
#pragma unroll
    for (int v = 0; v < 4; v++) {
      int l = t * 4 + v;
      int i = l >> 4, k = l & 15;
      As[k][i] = W[(long long)(m0 + i) * K + k0 + k];
    }
#pragma unroll
    for (int v = 0; v < 4; v++) {
      int l = t * 4 + v;
      int k = l >> 6, j = l & 63;
      float x = Xb[(long long)(k0 + k) * N + n0 + j];
      if (Ab) x += Ab[(long long)(k0 + k) * N + n0 + j];
      Bs[k][j] = x;
    }
    __syncthreads();
#pragma unroll
    for (int k = 0; k < TK; k++) {
      float a[4], bb[4];
#pragma unroll
      for (int ii = 0; ii < 4; ii++) a[ii] = As[k][ty * 4 + ii];
#pragma unroll
      for (int jj = 0; jj < 4; jj++) bb[jj] = Bs[k][tx * 4 + jj];
#pragma unroll
      for (int ii = 0; ii < 4; ii++)
#pragma unroll
        for (int jj = 0; jj < 4; jj++)
          acc[ii][jj] = fmaf(a[ii], bb[jj], acc[ii][jj]);
    }
    __syncthreads();
  }
#pragma unroll
  for (int ii = 0; ii < 4; ii++) {
    int m = m0 + ty * 4 + ii;
    float sh = bias ? bias[m] : 0.f;
    bool dobn = (bng != nullptr);
    float bnsc = 0.f, bnsh = 0.f;
    if (dobn) {
      bnsc = bng[m] * rsqrtf(bnv[m] + 1e-5f);
      bnsh = bnb[m] - bnm[m] * bnsc;
    }
#pragma unroll
    for (int jj = 0; jj < 4; jj++) {
      int n = n0 + tx * 4 + jj;
      float v = acc[ii][jj] + sh;
      if (dobn) v = fmaxf(v * bnsc + bnsh, 0.f);
      if (Res) v += Res[(long long)b * srB + (long long)m * N + n];
      Y[(long long)b * syB + (long long)m * N + n] = v;
    }
  }
}

// bf16x3 product accumulate over both 32-K chunks, smallest terms first
#define BF3_ACC(z, Ah0, Ah1, Am0, Am1, Al0, Al1, Bh0, Bh1, Bm0, Bm1, Bl0, Bl1)  \
  do {                                                                          \
    z = __builtin_amdgcn_mfma_f32_16x16x32_bf16(Al0, Bh0, z, 0, 0, 0);          \
    z = __builtin_amdgcn_mfma_f32_16x16x32_bf16(Al1, Bh1, z, 0, 0, 0);          \
    z = __builtin_amdgcn_mfma_f32_16x16x32_bf16(Ah0, Bl0, z, 0, 0, 0);          \
    z = __builtin_amdgcn_mfma_f32_16x16x32_bf16(Ah1, Bl1, z, 0, 0, 0);          \
    z = __builtin_amdgcn_mfma_f32_16x16x32_bf16(Am0, Bm0, z, 0, 0, 0);          \
    z = __builtin_amdgcn_mfma_f32_16x16x32_bf16(Am1, Bm1, z, 0, 0, 0);          \
    z = __builtin_amdgcn_mfma_f32_16x16x32_bf16(Am0, Bh0, z, 0, 0, 0);          \
    z = __builtin_amdgcn_mfma_f32_16x16x32_bf16(Am1, Bh1, z, 0, 0, 0);          \
    z = __builtin_amdgcn_mfma_f32_16x16x32_bf16(Ah0, Bm0, z, 0, 0, 0);          \
    z = __builtin_amdgcn_mfma_f32_16x16x32_bf16(Ah1, Bm1, z, 0, 0, 0);          \
    z = __builtin_amdgcn_mfma_f32_16x16x32_bf16(Ah0, Bh0, z, 0, 0, 0);          \
    z = __builtin_amdgcn_mfma_f32_16x16x32_bf16(Ah1, Bh1, z, 0, 0, 0);          \
  } while (0)

// E[b,n,m] = sum_d q[b,d,n]*q[b,d,m] via bf16x3 MFMA; q f32 [B][CQ][N]
// grid (N/64 m, N/64 n, B), block 256 = 4 waves (wave w -> n-rows w*16..+15)
__global__ __launch_bounds__(256) void energy_mfma(const float* __restrict__ q,
                                                   float* __restrict__ E) {
  const int N = N_DIM;
  int b = blockIdx.z;
  int n0 = blockIdx.y * 64;  // rows
  int m0 = blockIdx.x * 64;  // cols
  int t = threadIdx.x;
  __shared__ short qnh[64][72], qnm[64][72], qnl[64][72];
  __shared__ short qmh[64][72], qmm[64][72], qml[64][72];
  const float* qb = q + (long long)b * CQ * N;
  int cg = (t & 15) * 4, dr = t >> 4;
#pragma unroll
  for (int it = 0; it < 4; it++) {
    int d = dr + it * 16;
    float4 vn = *(const float4*)(qb + (long long)d * N + n0 + cg);
    float4 vm = *(const float4*)(qb + (long long)d * N + m0 + cg);
    float va[4] = {vn.x, vn.y, vn.z, vn.w};
    float vc[4] = {vm.x, vm.y, vm.z, vm.w};
#pragma unroll
    for (int j = 0; j < 4; j++) {
      unsigned short h, m, l;
      split_bf16x3(va[j], h, m, l);
      qnh[cg + j][d] = (short)h;
      qnm[cg + j][d] = (short)m;
      qnl[cg + j][d] = (short)l;
      split_bf16x3(vc[j], h, m, l);
      qmh[cg + j][d] = (short)h;
      qmm[cg + j][d] = (short)m;
      qml[cg + j][d] = (short)l;
    }
  }
  __syncthreads();
  int w = t >> 6, lane = t & 63, quad = lane >> 4, lm = lane & 15;
  int ar = w * 16 + lm;
  short8 ah0 = *(const short8*)(&qnh[ar][quad * 8]);
  short8 ah1 = *(const short8*)(&qnh[ar][32 + quad * 8]);
  short8 am0 = *(const short8*)(&qnm[ar][quad * 8]);
  short8 am1 = *(const short8*)(&qnm[ar][32 + quad * 8]);
  short8 al0 = *(const short8*)(&qnl[ar][quad * 8]);
  short8 al1 = *(const short8*)(&qnl[ar][32 + quad * 8]);
  long long base = (long long)b * N * N;
#pragma unroll
  for (int ms = 0; ms < 4; ms++) {
    int br = ms * 16 + lm;
    short8 bh0 = *(const short8*)(&qmh[br][quad * 8]);
    short8 bh1 = *(const short8*)(&qmh[br][32 + quad * 8]);
    short8 bm0 = *(const short8*)(&qmm[br][quad * 8]);
    short8 bm1 = *(const short8*)(&qmm[br][32 + quad * 8]);
    short8 bl0 = *(const short8*)(&qml[br][quad * 8]);
    short8 bl1 = *(const short8*)(&qml[br][32 + quad * 8]);
    floatx4 z = {0.f, 0.f, 0.f, 0.f};
    BF3_ACC(z, ah0, ah1, am0, am1, al0, al1, bh0, bh1, bm0, bm1, bl0, bl1);
#pragma unroll
    for (int r = 0; r < 4; r++)
      E[base + (long long)(n0 + w * 16 + quad * 4 + r) * N + (m0 + ms * 16 + lm)] =
          z[r];
  }
}

// row softmax in place; one block (256 thr) per row of length 2048  [round-1]
__global__ void softmax_kernel(float* __restrict__ E) {
  const int N = N_DIM;
  long long row = blockIdx.x;
  float* p = E + row * N;
  int t = threadIdx.x;
  float v[8];
#pragma unroll
  for (int i = 0; i < 8; i++) v[i] = p[t + i * 256];
  float m = v[0];
#pragma unroll
  for (int i = 1; i < 8; i++) m = fmaxf(m, v[i]);
  for (int o = 32; o > 0; o >>= 1) m = fmaxf(m, __shfl_down(m, o, 64));
  __shared__ float red[4];
  int wid = t >> 6, lane = t & 63;
  if (lane == 0) red[wid] = m;
  __syncthreads();
  m = fmaxf(fmaxf(red[0], red[1]), fmaxf(red[2], red[3]));
  __syncthreads();
  float s = 0.f;
#pragma unroll
  for (int i = 0; i < 8; i++) {
    v[i] = __expf(v[i] - m);
    s += v[i];
  }
  for (int o = 32; o > 0; o >>= 1) s += __shfl_down(s, o, 64);
  if (lane == 0) red[wid] = s;
  __syncthreads();
  s = red[0] + red[1] + red[2] + red[3];
  float inv = 1.0f / s;
#pragma unroll
  for (int i = 0; i < 8; i++) p[t + i * 256] = v[i] * inv;
}

// cs[b,m] = sum_n att[b,n,m]   [round-1]
__global__ void colsum_kernel(const float* __restrict__ E, float* __restrict__ cs) {
  const int N = N_DIM;
  int t = threadIdx.x;
  int tx = t & 63, tz = t >> 6;
  int m = blockIdx.x * 64 + tx;
  int b = blockIdx.y;
  const float* p = E + (long long)b * N * N + m;
  float s = 0.f;
  for (int n = tz; n < N; n += 4) s += p[(long long)n * N];
  __shared__ float sm[4][64];
  sm[tz][tx] = s;
  __syncthreads();
  if (tz == 0) cs[(long long)b * N + m] = sm[0][tx] + sm[1][tx] + sm[2][tx] + sm[3][tx];
}

// D[b,c,n] = Hp[b,c,n] - (sum_k val[b,c,k]*att[b,k,n]) / (1e-9 + cs[b,n])
// bf16x3 MFMA; grid (N/64 m, C/64 c, B), block 256 = 4 waves
__global__ __launch_bounds__(256) void pv_mfma(
    const float* __restrict__ val, const float* __restrict__ att,
    const float* __restrict__ cs, const float* __restrict__ Hp, long long shB,
    float* __restrict__ D) {
  const int N = N_DIM;
  int b = blockIdx.z;
  int c0 = blockIdx.y * 64;
  int m0 = blockIdx.x * 64;
  int t = threadIdx.x;
  int w = t >> 6, lane = t & 63, quad = lane >> 4, lm = lane & 15;
  __shared__ short ath[64][72], atm[64][72], atl[64][72];  // att^T [m_local][n_local]
  __shared__ short vsh[64][72], vsm[64][72], vsl[64][72];  // val   [c_local][n_local]
  const float* vb = val + (long long)b * C_DIM * N;
  const float* ab = att + (long long)b * N * N;
  floatx4 pacc[4];
#pragma unroll
  for (int ms = 0; ms < 4; ms++) {
    floatx4 z = {0.f, 0.f, 0.f, 0.f};
    pacc[ms] = z;
  }
  int cg = (t & 15) * 4, rr = t >> 4;
  for (int n0 = 0; n0 < N; n0 += 64) {
#pragma unroll
    for (int it = 0; it < 4; it++) {
      int rl = rr + it * 16;  // att n-local row; also val c-local row
      float4 av = *(const float4*)(ab + (long long)(n0 + rl) * N + m0 + cg);
      float4 vv = *(const float4*)(vb + (long long)(c0 + rl) * N + n0 + cg);
      float aa[4] = {av.x, av.y, av.z, av.w};
      float ww[4] = {vv.x, vv.y, vv.z, vv.w};
#pragma unroll
      for (int j = 0; j < 4; j++) {
        unsigned short h, m, l;
        split_bf16x3(aa[j], h, m, l);
        ath[cg + j][rl] = (short)h;  // transpose att -> [m][n]
        atm[cg + j][rl] = (short)m;
        atl[cg + j][rl] = (short)l;
        split_bf16x3(ww[j], h, m, l);
        vsh[rl][cg + j] = (short)h;  // val stays [c][n]
        vsm[rl][cg + j] = (short)m;
        vsl[rl][cg + j] = (short)l;
      }
    }
    __syncthreads();
    int ar = w * 16 + lm;
    short8 Ah0 = *(const short8*)(&vsh[ar][quad * 8]);
    short8 Ah1 = *(const short8*)(&vsh[ar][32 + quad * 8]);
    short8 Am0 = *(const short8*)(&vsm[ar][quad * 8]);
    short8 Am1 = *(const short8*)(&vsm[ar][32 + quad * 8]);
    short8 Al0 = *(const short8*)(&vsl[ar][quad * 8]);
    short8 Al1 = *(const short8*)(&vsl[ar][32 + quad * 8]);
#pragma unroll
    for (int ms = 0; ms < 4; ms++) {
      int br = ms * 16 + lm;
      short8 Bh0 = *(const short8*)(&ath[br][quad * 8]);
      short8 Bh1 = *(const short8*)(&ath[br][32 + quad * 8]);
      short8 Bm0 = *(const short8*)(&atm[br][quad * 8]);
      short8 Bm1 = *(const short8*)(&atm[br][32 + quad * 8]);
      short8 Bl0 = *(const short8*)(&atl[br][quad * 8]);
      short8 Bl1 = *(const short8*)(&atl[br][32 + quad * 8]);
      floatx4 z = pacc[ms];
      BF3_ACC(z, Ah0, Ah1, Am0, Am1, Al0, Al1, Bh0, Bh1, Bm0, Bm1, Bl0, Bl1);
      pacc[ms] = z;
    }
    __syncthreads();
  }
  const float* hp = Hp + (long long)b * shB;
  float* db = D + (long long)b * C_DIM * N;
#pragma unroll
  for (int ms = 0; ms < 4; ms++) {
    int m = m0 + ms * 16 + lm;
    float inv = 1.0f / (1e-9f + cs[(long long)b * N + m]);
#pragma unroll
    for (int r = 0; r < 4; r++) {
      int c = c0 + w * 16 + quad * 4 + r;
      db[(long long)c * N + m] = hp[(long long)c * N + m] - pacc[ms][r] * inv;
    }
  }
}

extern "C" void kernel_launch(void* const* d_in, const int* in_sizes, int n_in,
                              void* d_out, int out_size, void* d_ws, size_t ws_size,
                              hipStream_t stream) {
  const float* x = (const float*)d_in[0];
  const float* xyz = (const float*)d_in[1];
  const float* conv1_w = (const float*)d_in[2];
  const float* convpos_w = (const float*)d_in[3];
  const float* bn1_g = (const float*)d_in[4];
  const float* bn1_b = (const float*)d_in[5];
  const float* bn1_m = (const float*)d_in[6];
  const float* bn1_v = (const float*)d_in[7];
  const float* Wqk = (const float*)d_in[8];   // [4,64,256]
  const float* Wv = (const float*)d_in[9];    // [4,256,256]
  const float* bv = (const float*)d_in[10];   // [4,256]
  const float* Wt = (const float*)d_in[11];   // [4,256,256]
  const float* bt = (const float*)d_in[12];   // [4,256]
  const float* bng = (const float*)d_in[13];
  const float* bnb = (const float*)d_in[14];
  const float* bnm = (const float*)d_in[15];
  const float* bnv = (const float*)d_in[16];
  float* out = (float*)d_out;

  const long long BCN = (long long)B_DIM * C_DIM * N_DIM;
  const long long CN = (long long)C_DIM * N_DIM;
  float* ws = (float*)d_ws;
  float* pos = ws;                                   // BCN
  float* h0 = pos + BCN;                             // BCN
  float* qbuf = h0 + BCN;                            // B*CQ*N
  float* valb = qbuf + (long long)B_DIM * CQ * N_DIM;  // BCN
  float* dbuf = valb + BCN;                          // BCN
  float* csum = dbuf + BCN;                          // B*N
  float* att = csum + (long long)B_DIM * N_DIM;      // B*N*N

  dim3 blk(256);

  pos_kernel<<<dim3(N_DIM / 256, C_DIM, B_DIM), blk, 0, stream>>>(convpos_w, xyz, pos);

  // h0 = relu(bn1(conv1_w @ x))
  gemm_wx<<<dim3(N_DIM / TN, C_DIM / TM, B_DIM), blk, 0, stream>>>(
      conv1_w, x, CN, nullptr, 0, nullptr,
      bn1_g, bn1_b, bn1_m, bn1_v, nullptr, 0, h0, CN, C_DIM, C_DIM);

  for (int i = 0; i < 4; i++) {
    const float* hp = (i == 0) ? h0 : out + (long long)(i - 1) * CN;
    long long shp = (i == 0) ? CN : 4 * CN;

    // q = Wqk_i @ (h + pos)   f32 [B][64][N]
    gemm_wx<<<dim3(N_DIM / TN, CQ / TM, B_DIM), blk, 0, stream>>>(
        Wqk + (long long)i * CQ * C_DIM, hp, shp, pos, CN, nullptr,
        nullptr, nullptr, nullptr, nullptr, nullptr, 0,
        qbuf, (long long)CQ * N_DIM, CQ, C_DIM);

    // val = Wv_i @ (h + pos) + bv_i   f32 [B][C][N]
    gemm_wx<<<dim3(N_DIM / TN, C_DIM / TM, B_DIM), blk, 0, stream>>>(
        Wv + (long long)i * C_DIM * C_DIM, hp, shp, pos, CN, bv + i * C_DIM,
        nullptr, nullptr, nullptr, nullptr, nullptr, 0,
        valb, CN, C_DIM, C_DIM);

    energy_mfma<<<dim3(N_DIM / 64, N_DIM / 64, B_DIM), blk, 0, stream>>>(qbuf, att);

    softmax_kernel<<<dim3(B_DIM * N_DIM), blk, 0, stream>>>(att);

    colsum_kernel<<<dim3(N_DIM / 64, B_DIM), blk, 0, stream>>>(att, csum);

    pv_mfma<<<dim3(N_DIM / 64, C_DIM / 64, B_DIM), blk, 0, stream>>>(
        valb, att, csum, hp, shp, dbuf);

    // out_i = h + relu(bn_i(Wt_i @ d + bt_i))
    gemm_wx<<<dim3(N_DIM / TN, C_DIM / TM, B_DIM), blk, 0, stream>>>(
        Wt + (long long)i * C_DIM * C_DIM, dbuf, CN, nullptr, 0, bt + i * C_DIM,
        bng + i * C_DIM, bnb + i * C_DIM, bnm + i * C_DIM, bnv + i * C_DIM,
        hp, shp, out + (long long)i * CN, 4 * CN, C_DIM, C_DIM);
  }
}